// Round 12
// baseline (206.771 us; speedup 1.0000x reference)
//
#include <hip/hip_runtime.h>
#include <math.h>

typedef __bf16 bf16_t;
typedef bf16_t bf16x8 __attribute__((ext_vector_type(8)));
typedef bf16_t bf16x4 __attribute__((ext_vector_type(4)));
typedef short  s16x4  __attribute__((ext_vector_type(4)));
typedef float  f32x4  __attribute__((ext_vector_type(4)));

#define DIM_   1024
#define NHEADS 16
#define HDIM   64
#define SEQ    2048
#define BATCH  2

// log2(e)/8 : folded into q at RoPE time so attention softmax is exp2(s)
#define QK_SCALE 0.18033688011112042f
// log2(10000)/32
#define ROPE_LF 0.41524101186092029f

__device__ __forceinline__ s16x4 as_s16x4(bf16x4 v) {
    union { bf16x4 b; s16x4 s; } u; u.b = v; return u.s;
}

// async global->LDS, 16 B per lane; LDS dest = wave-uniform base + lane*16
__device__ __forceinline__ void gld16(const bf16_t* g, bf16_t* l) {
    __builtin_amdgcn_global_load_lds(
        (const __attribute__((address_space(1))) void*)g,
        (__attribute__((address_space(3))) void*)l, 16, 0, 0);
}

// ---------------------------------------------------------------------------
// Fused fp32->bf16 cast of x, w_qkv, w_out.
// ---------------------------------------------------------------------------
#define XCNT   (4096u * 1024u)
#define WQCNT  (3072u * 1024u)
#define WOCNT  (1024u * 1024u)
__global__ __launch_bounds__(256) void cast3(const float* __restrict__ s0,
                                             const float* __restrict__ s1,
                                             const float* __restrict__ s2,
                                             bf16_t* __restrict__ d0,
                                             bf16_t* __restrict__ d1,
                                             bf16_t* __restrict__ d2) {
    size_t i = ((size_t)blockIdx.x * 256 + threadIdx.x) * 8;
    const float* s; bf16_t* d; size_t off;
    if (i < XCNT)               { s = s0; d = d0; off = i; }
    else if (i < XCNT + WQCNT)  { s = s1; d = d1; off = i - XCNT; }
    else                        { s = s2; d = d2; off = i - XCNT - WQCNT; }
    float4 a = *(const float4*)(s + off);
    float4 b = *(const float4*)(s + off + 4);
    bf16x8 o = { (bf16_t)a.x, (bf16_t)a.y, (bf16_t)a.z, (bf16_t)a.w,
                 (bf16_t)b.x, (bf16_t)b.y, (bf16_t)b.z, (bf16_t)b.w };
    *(bf16x8*)(d + off) = o;
}

// ---------------------------------------------------------------------------
// QKV GEMM, 128x128 tile, BK=32, LDS double-buffer 2-phase (R8), fused RoPE
// epilogue (R11). Layouts: q dense [m][1024]; kt[bh][s][d]; vt[bh][s/16][d][s%16].
// ---------------------------------------------------------------------------
__global__ __launch_bounds__(256) void gemm_qkv(const bf16_t* __restrict__ A,
                                                const bf16_t* __restrict__ B,
                                                bf16_t* __restrict__ qb,
                                                bf16_t* __restrict__ kt,
                                                bf16_t* __restrict__ vt,
                                                int M, int N, int K) {
    __shared__ __align__(16) bf16_t As[2][128 * 32];
    __shared__ __align__(16) bf16_t Bs[2][128 * 32];
    const int tid  = threadIdx.x;
    const int m0   = blockIdx.y * 128;
    const int n0   = blockIdx.x * 128;
    const int w    = tid >> 6;
    const int lane = tid & 63;
    const int m16  = lane & 15;
    const int quad = lane >> 4;
    const int wm   = (w >> 1) * 64;
    const int wn   = (w & 1) * 64;
    const int lrow = lane >> 2;
    const int lcol = (lane & 3) * 8;

    const bf16_t* pa0 = A + (size_t)(m0 + w * 16 + lrow) * K + lcol;
    const bf16_t* pb0 = B + (size_t)(n0 + w * 16 + lrow) * K + lcol;
    const int sOffA0 = (w * 16) * 32;
    const int sOffA1 = (64 + w * 16) * 32;

    gld16(pa0, (bf16_t*)As + sOffA0);
    gld16(pa0 + (size_t)64 * K, (bf16_t*)As + sOffA1);
    gld16(pb0, (bf16_t*)Bs + sOffA0);
    gld16(pb0 + (size_t)64 * K, (bf16_t*)Bs + sOffA1);
    __syncthreads();

    f32x4 acc[4][4] = {};
    int buf = 0;

    for (int k0 = 0; k0 < K; k0 += 32) {
        const int nb = buf ^ 1;
        if (k0 + 32 < K) {
            gld16(pa0 + k0 + 32, (bf16_t*)As + nb * 4096 + sOffA0);
            gld16(pa0 + (size_t)64 * K + k0 + 32, (bf16_t*)As + nb * 4096 + sOffA1);
            gld16(pb0 + k0 + 32, (bf16_t*)Bs + nb * 4096 + sOffA0);
            gld16(pb0 + (size_t)64 * K + k0 + 32, (bf16_t*)Bs + nb * 4096 + sOffA1);
        }
        const bf16_t* sA = (const bf16_t*)As + buf * 4096;
        const bf16_t* sB = (const bf16_t*)Bs + buf * 4096;
        bf16x8 af[4], bfr[4];
#pragma unroll
        for (int i = 0; i < 4; ++i)
            af[i] = *(const bf16x8*)(sA + (wm + i * 16 + m16) * 32 + quad * 8);
#pragma unroll
        for (int j = 0; j < 4; ++j)
            bfr[j] = *(const bf16x8*)(sB + (wn + j * 16 + m16) * 32 + quad * 8);
#pragma unroll
        for (int i = 0; i < 4; ++i)
#pragma unroll
            for (int j = 0; j < 4; ++j)
                acc[i][j] = __builtin_amdgcn_mfma_f32_16x16x32_bf16(af[i], bfr[j], acc[i][j], 0, 0, 0);
        __syncthreads();
        buf = nb;
    }

    const int b = m0 >> 11;
    if (n0 < 2 * DIM_) {
        // ---- q or k with fused RoPE ----
        const bool isq = (n0 < DIM_);
        const int  sg  = (m0 & (SEQ - 1)) + wm;  // + i*16 + quad*4 + r = seq pos
        const float osc = isq ? QK_SCALE : 1.0f;
        const bool even = ((m16 & 1) == 0);
#pragma unroll
        for (int j = 0; j < 4; ++j) {
            const int n = (n0 & (DIM_ - 1)) + wn + j * 16 + m16;
            const int h = n >> 6;
            const int t = (n & 63) >> 1;
            const int dout = even ? t : 32 + t;
            const float freq = exp2f(-ROPE_LF * (float)t);
            float stp_s, stp_c;
            sincosf(freq, &stp_s, &stp_c);       // rotation step (s -> s+1)
#pragma unroll
            for (int i = 0; i < 4; ++i) {
                float sa, ca;
                sincosf((float)(sg + i * 16 + quad * 4) * freq, &sa, &ca);
#pragma unroll
                for (int r = 0; r < 4; ++r) {
                    const float mine  = acc[i][j][r];
                    const float other = __shfl_xor(mine, 1);
                    const float outv  = (mine * ca + (even ? -other : other) * sa) * osc;
                    if (isq) {
                        qb[(size_t)(m0 + wm + i * 16 + quad * 4 + r) * DIM_ + h * 64 + dout] = (bf16_t)outv;
                    } else {
                        kt[((size_t)(b * 16 + h) * SEQ + (sg + i * 16 + quad * 4 + r)) * 64 + dout] = (bf16_t)outv;
                    }
                    // rotate (ca,sa) by step for next r
                    const float nc = ca * stp_c - sa * stp_s;
                    sa = sa * stp_c + ca * stp_s;
                    ca = nc;
                }
            }
        }
    } else {
        // ---- v: vt[((b*16+h)*128 + s/16)*64 + d][s%16] ----
#pragma unroll
        for (int j = 0; j < 4; ++j) {
            const int n = n0 - 2 * DIM_ + wn + j * 16 + m16;
            const int h = n >> 6;
            const int d = n & 63;
#pragma unroll
            for (int i = 0; i < 4; ++i) {
                const int s0 = (m0 & (SEQ - 1)) + wm + i * 16;
                const int kb = s0 >> 4;
                bf16x4 ov = { (bf16_t)acc[i][j][0], (bf16_t)acc[i][j][1],
                              (bf16_t)acc[i][j][2], (bf16_t)acc[i][j][3] };
                *(bf16x4*)(vt + ((size_t)((b * 16 + h) * 128 + kb) * 64 + d) * 16 + quad * 4) = ov;
            }
        }
    }
}

// ---------------------------------------------------------------------------
// Output GEMM, 128x64 tile, LDS double-buffer 2-phase (R8).
// ---------------------------------------------------------------------------
__global__ __launch_bounds__(256) void gemm_out64(const bf16_t* __restrict__ A,
                                                  const bf16_t* __restrict__ B,
                                                  const float* __restrict__ bias,
                                                  float* __restrict__ C,
                                                  int M, int N, int K) {
    __shared__ __align__(16) bf16_t As[2][128 * 32];
    __shared__ __align__(16) bf16_t Bs[2][64 * 32];
    const int tid  = threadIdx.x;
    const int m0   = blockIdx.y * 128;
    const int n0   = blockIdx.x * 64;
    const int w    = tid >> 6;
    const int lane = tid & 63;
    const int m16  = lane & 15;
    const int quad = lane >> 4;
    const int wm   = (w >> 1) * 64;
    const int wn   = (w & 1) * 32;
    const int lrow = lane >> 2;
    const int lcol = (lane & 3) * 8;

    const bf16_t* pa0 = A + (size_t)(m0 + w * 16 + lrow) * K + lcol;
    const bf16_t* pb0 = B + (size_t)(n0 + w * 16 + lrow) * K + lcol;
    const int sOff0 = (w * 16) * 32;
    const int sOff1 = (64 + w * 16) * 32;

    gld16(pa0, (bf16_t*)As + sOff0);
    gld16(pa0 + (size_t)64 * K, (bf16_t*)As + sOff1);
    gld16(pb0, (bf16_t*)Bs + sOff0);
    __syncthreads();

    f32x4 acc[4][2] = {};
    int buf = 0;

    for (int k0 = 0; k0 < K; k0 += 32) {
        const int nb = buf ^ 1;
        if (k0 + 32 < K) {
            gld16(pa0 + k0 + 32, (bf16_t*)As + nb * 4096 + sOff0);
            gld16(pa0 + (size_t)64 * K + k0 + 32, (bf16_t*)As + nb * 4096 + sOff1);
            gld16(pb0 + k0 + 32, (bf16_t*)Bs + nb * 2048 + sOff0);
        }
        const bf16_t* sA = (const bf16_t*)As + buf * 4096;
        const bf16_t* sB = (const bf16_t*)Bs + buf * 2048;
        bf16x8 af[4], bfr[2];
#pragma unroll
        for (int i = 0; i < 4; ++i)
            af[i] = *(const bf16x8*)(sA + (wm + i * 16 + m16) * 32 + quad * 8);
#pragma unroll
        for (int j = 0; j < 2; ++j)
            bfr[j] = *(const bf16x8*)(sB + (wn + j * 16 + m16) * 32 + quad * 8);
#pragma unroll
        for (int i = 0; i < 4; ++i)
#pragma unroll
            for (int j = 0; j < 2; ++j)
                acc[i][j] = __builtin_amdgcn_mfma_f32_16x16x32_bf16(af[i], bfr[j], acc[i][j], 0, 0, 0);
        __syncthreads();
        buf = nb;
    }

#pragma unroll
    for (int j = 0; j < 2; ++j) {
        const int col = n0 + wn + j * 16 + m16;
        const float bv = bias[col];
#pragma unroll
        for (int i = 0; i < 4; ++i)
#pragma unroll
            for (int r = 0; r < 4; ++r)
                C[(size_t)(m0 + wm + i * 16 + quad * 4 + r) * N + col] = acc[i][j][r] + bv;
    }
}

// ---------------------------------------------------------------------------
// Flash attention (R12). Counters said latency-bound (per-SIMD duty ~12%,
// occupancy ~18%, FETCH 2.8x unique): (a) PREFETCH DEPTH 2 — 4 named register
// buffers A-D, loads issued 2 tiles ahead (~640 cyc compute in flight per
// load); tail loads past the head run into adjacent ws buffers (allocated,
// unused) so no guards. (b) XCD-BIJECTIVE SWIZZLE — 1D grid, each XCD owns 4
// whole heads (2 MB K/V < 4 MB L2) so K/V loads hit its own L2.
// ---------------------------------------------------------------------------
__global__ __launch_bounds__(256) void attn_mfma(const bf16_t* __restrict__ qb,
                                                 const bf16_t* __restrict__ kt,
                                                 const bf16_t* __restrict__ vt,
                                                 bf16_t* __restrict__ out) {
    __shared__ __align__(16) char smem[17664];
    float* Ored = (float*)smem;               // 16640 B
    float* Lred = (float*)(smem + 16640);     // 1024 B

    const int tid  = threadIdx.x;
    const int w    = tid >> 6;
    const int lane = tid & 63;
    const int m16  = lane & 15;
    const int quad = lane >> 4;

    // XCD-bijective swizzle: 1024 blocks, XCD x owns swz [x*128, x*128+128)
    // = heads [x*4, x*4+4) (32 q-blocks per head).
    const int bid = blockIdx.x;
    const int swz = (bid & 7) * 128 + (bid >> 3);
    const int bh  = swz >> 5;
    const int q0  = (swz & 31) * 64;
    const int b   = bh >> 4;
    const int hh  = bh & 15;

    // Q fragments from dense qb
    bf16x8 qf[4][2];
#pragma unroll
    for (int n = 0; n < 4; ++n)
#pragma unroll
        for (int c = 0; c < 2; ++c)
            qf[n][c] = *(const bf16x8*)(qb + (size_t)(b * SEQ + q0 + n * 16 + m16) * DIM_ +
                                        hh * HDIM + c * 32 + quad * 8);

    f32x4 o[4][4] = {};
    float lp[4] = {};

    // fragment pointers (tile 0); advance 4096 elements per tile
    const bf16_t* kp = kt + ((size_t)bh * SEQ + w * 16 + m16) * 64 + quad * 8;
    const bf16_t* vp = vt + (((size_t)bh * 128 + w) * 64 + m16) * 16 + quad * 4;

#define LOAD_TILE(AK0, AK1, VA)                                \
    do {                                                       \
        AK0 = *(const bf16x8*)(kp);                            \
        AK1 = *(const bf16x8*)(kp + 32);                       \
        VA[0] = *(const bf16x4*)(vp);                          \
        VA[1] = *(const bf16x4*)(vp + 256);                    \
        VA[2] = *(const bf16x4*)(vp + 512);                    \
        VA[3] = *(const bf16x4*)(vp + 768);                    \
        kp += 4096; vp += 4096;                                \
    } while (0)

#define COMPUTE_TILE(AK0, AK1, VA)                                                 \
    do {                                                                           \
        s16x4 pb[4];                                                               \
        _Pragma("unroll")                                                          \
        for (int n = 0; n < 4; ++n) {                                              \
            f32x4 c = {};                                                          \
            c = __builtin_amdgcn_mfma_f32_16x16x32_bf16(AK0, qf[n][0], c, 0, 0, 0); \
            c = __builtin_amdgcn_mfma_f32_16x16x32_bf16(AK1, qf[n][1], c, 0, 0, 0); \
            bf16x4 pv;                                                             \
            _Pragma("unroll")                                                      \
            for (int r = 0; r < 4; ++r) {                                          \
                const float pp = __builtin_amdgcn_exp2f(c[r]);                     \
                lp[n] += pp;                                                       \
                pv[r] = (bf16_t)pp;                                                \
            }                                                                      \
            pb[n] = as_s16x4(pv);                                                  \
        }                                                                          \
        __builtin_amdgcn_s_setprio(1);                                             \
        _Pragma("unroll")                                                          \
        for (int ds = 0; ds < 4; ++ds)                                             \
            _Pragma("unroll")                                                      \
            for (int n = 0; n < 4; ++n)                                            \
                o[ds][n] = __builtin_amdgcn_mfma_f32_16x16x16bf16_1k(               \
                    as_s16x4(VA[ds]), pb[n], o[ds][n], 0, 0, 0);                   \
        __builtin_amdgcn_s_setprio(0);                                             \
    } while (0)

    bf16x8 akA0, akA1, akB0, akB1, akC0, akC1, akD0, akD1;
    bf16x4 vaA[4], vaB[4], vaC[4], vaD[4];

    LOAD_TILE(akA0, akA1, vaA);          // tile 0
    LOAD_TILE(akB0, akB1, vaB);          // tile 1
    for (int t = 0; t < 32; t += 4) {
        LOAD_TILE(akC0, akC1, vaC);      // t+2
        COMPUTE_TILE(akA0, akA1, vaA);   // t
        LOAD_TILE(akD0, akD1, vaD);      // t+3
        COMPUTE_TILE(akB0, akB1, vaB);   // t+1
        LOAD_TILE(akA0, akA1, vaA);      // t+4 (t=28: tile 32, OOB-safe in ws)
        COMPUTE_TILE(akC0, akC1, vaC);   // t+2
        LOAD_TILE(akB0, akB1, vaB);      // t+5 (t=28: tile 33, OOB-safe in ws)
        COMPUTE_TILE(akD0, akD1, vaD);   // t+3
    }
#undef LOAD_TILE
#undef COMPUTE_TILE

    // ---- l reduction: over quads (shfl), then over waves (LDS) ----
#pragma unroll
    for (int n = 0; n < 4; ++n) {
        lp[n] += __shfl_xor(lp[n], 16);
        lp[n] += __shfl_xor(lp[n], 32);
    }
    if (quad == 0) {
#pragma unroll
        for (int n = 0; n < 4; ++n) Lred[w * 64 + n * 16 + m16] = lp[n];
    }
    __syncthreads();
    const float linv = 1.0f / (Lred[lane] + Lred[64 + lane] + Lred[128 + lane] + Lred[192 + lane]);

    // ---- O reduction: 4 phases; all waves sum+store ----
    const size_t obase = (size_t)(b * SEQ + q0 + lane) * DIM_ + hh * HDIM;
#pragma unroll
    for (int p = 0; p < 4; ++p) {
        __syncthreads();
#pragma unroll
        for (int n = 0; n < 4; ++n)
#pragma unroll
            for (int r = 0; r < 4; ++r)
                Ored[w * 1040 + (quad * 4 + r) * 65 + n * 16 + m16] = o[p][n][r];
        __syncthreads();
        union { bf16_t e[4]; bf16x4 v; } ob;
#pragma unroll
        for (int d = 0; d < 4; ++d) {
            const int dd = w * 4 + d;
            const float v = Ored[dd * 65 + lane] + Ored[1040 + dd * 65 + lane] +
                            Ored[2080 + dd * 65 + lane] + Ored[3120 + dd * 65 + lane];
            ob.e[d] = (bf16_t)(v * linv);
        }
        *(bf16x4*)(out + obase + p * 16 + w * 4) = ob.v;
    }
}

// ---------------------------------------------------------------------------
extern "C" void kernel_launch(void* const* d_in, const int* in_sizes, int n_in,
                              void* d_out, int out_size, void* d_ws, size_t ws_size,
                              hipStream_t stream) {
    const float* x     = (const float*)d_in[0];
    const float* w_qkv = (const float*)d_in[1];
    const float* w_out = (const float*)d_in[2];
    const float* b_out = (const float*)d_in[3];
    float* out = (float*)d_out;

    const int M = BATCH * SEQ;  // 4096

    bf16_t* q_b    = (bf16_t*)d_ws;                         // 4096x1024
    bf16_t* attn_b = q_b + (size_t)M * DIM_;                // 4096x1024
    bf16_t* kt_b   = attn_b + (size_t)M * DIM_;             // 32 heads x 2048 x 64
    bf16_t* vt_b   = kt_b + (size_t)M * DIM_;               // 32 heads x 128 x 64 x 16
    bf16_t* xb     = vt_b + (size_t)M * DIM_;               // 4096x1024 (also OOB pad for vt)
    bf16_t* wqkvb  = xb + (size_t)M * DIM_;                 // 3072x1024
    bf16_t* woutb  = wqkvb + (size_t)3 * DIM_ * DIM_;       // 1024x1024

    // 0) cast x, w_qkv, w_out to bf16
    cast3<<<(XCNT + WQCNT + WOCNT) / (256 * 8), 256, 0, stream>>>(
        x, w_qkv, w_out, xb, wqkvb, woutb);

    // 1) qkv = x @ w_qkv^T with FUSED RoPE (q dense+scaled; k -> kt; v -> vt)
    gemm_qkv<<<dim3(3 * DIM_ / 128, M / 128), 256, 0, stream>>>(
        xb, wqkvb, q_b, kt_b, vt_b, M, 3 * DIM_, DIM_);

    // 2) flash attention -> attn_b (1D grid, XCD-swizzled)
    attn_mfma<<<SEQ / 64 * BATCH * NHEADS, 256, 0, stream>>>(q_b, kt_b, vt_b, attn_b);

    // 3) out = attn @ w_out^T + b_out (fp32), 128x64 tiles -> 512 blocks (2/CU)
    gemm_out64<<<dim3(DIM_ / 64, M / 128), 256, 0, stream>>>(
        attn_b, woutb, b_out, out, M, DIM_, DIM_);
}

// Round 13
// 198.785 us; speedup vs baseline: 1.0402x; 1.0402x over previous
//
#include <hip/hip_runtime.h>
#include <math.h>

typedef __bf16 bf16_t;
typedef bf16_t bf16x8 __attribute__((ext_vector_type(8)));
typedef bf16_t bf16x4 __attribute__((ext_vector_type(4)));
typedef short  s16x4  __attribute__((ext_vector_type(4)));
typedef float  f32x4  __attribute__((ext_vector_type(4)));

#define DIM_   1024
#define NHEADS 16
#define HDIM   64
#define SEQ    2048
#define BATCH  2

// log2(e)/8 : folded into q at RoPE time so attention softmax is exp2(s)
#define QK_SCALE 0.18033688011112042f
// log2(10000)/32
#define ROPE_LF 0.41524101186092029f

__device__ __forceinline__ s16x4 as_s16x4(bf16x4 v) {
    union { bf16x4 b; s16x4 s; } u; u.b = v; return u.s;
}

// async global->LDS, 16 B per lane; LDS dest = wave-uniform base + lane*16
__device__ __forceinline__ void gld16(const bf16_t* g, bf16_t* l) {
    __builtin_amdgcn_global_load_lds(
        (const __attribute__((address_space(1))) void*)g,
        (__attribute__((address_space(3))) void*)l, 16, 0, 0);
}

// ---------------------------------------------------------------------------
// Fused fp32->bf16 cast of x, w_qkv, w_out.
// ---------------------------------------------------------------------------
#define XCNT   (4096u * 1024u)
#define WQCNT  (3072u * 1024u)
#define WOCNT  (1024u * 1024u)
__global__ __launch_bounds__(256) void cast3(const float* __restrict__ s0,
                                             const float* __restrict__ s1,
                                             const float* __restrict__ s2,
                                             bf16_t* __restrict__ d0,
                                             bf16_t* __restrict__ d1,
                                             bf16_t* __restrict__ d2) {
    size_t i = ((size_t)blockIdx.x * 256 + threadIdx.x) * 8;
    const float* s; bf16_t* d; size_t off;
    if (i < XCNT)               { s = s0; d = d0; off = i; }
    else if (i < XCNT + WQCNT)  { s = s1; d = d1; off = i - XCNT; }
    else                        { s = s2; d = d2; off = i - XCNT - WQCNT; }
    float4 a = *(const float4*)(s + off);
    float4 b = *(const float4*)(s + off + 4);
    bf16x8 o = { (bf16_t)a.x, (bf16_t)a.y, (bf16_t)a.z, (bf16_t)a.w,
                 (bf16_t)b.x, (bf16_t)b.y, (bf16_t)b.z, (bf16_t)b.w };
    *(bf16x8*)(d + off) = o;
}

// ---------------------------------------------------------------------------
// QKV GEMM, 128x128 tile, BK=32, LDS double-buffer 2-phase (R8), fused RoPE
// epilogue (R11). Layouts: q dense [m][1024]; kt[bh][s][d]; vt[bh][s/16][d][s%16].
// ---------------------------------------------------------------------------
__global__ __launch_bounds__(256) void gemm_qkv(const bf16_t* __restrict__ A,
                                                const bf16_t* __restrict__ B,
                                                bf16_t* __restrict__ qb,
                                                bf16_t* __restrict__ kt,
                                                bf16_t* __restrict__ vt,
                                                int M, int N, int K) {
    __shared__ __align__(16) bf16_t As[2][128 * 32];
    __shared__ __align__(16) bf16_t Bs[2][128 * 32];
    const int tid  = threadIdx.x;
    const int m0   = blockIdx.y * 128;
    const int n0   = blockIdx.x * 128;
    const int w    = tid >> 6;
    const int lane = tid & 63;
    const int m16  = lane & 15;
    const int quad = lane >> 4;
    const int wm   = (w >> 1) * 64;
    const int wn   = (w & 1) * 64;
    const int lrow = lane >> 2;
    const int lcol = (lane & 3) * 8;

    const bf16_t* pa0 = A + (size_t)(m0 + w * 16 + lrow) * K + lcol;
    const bf16_t* pb0 = B + (size_t)(n0 + w * 16 + lrow) * K + lcol;
    const int sOffA0 = (w * 16) * 32;
    const int sOffA1 = (64 + w * 16) * 32;

    gld16(pa0, (bf16_t*)As + sOffA0);
    gld16(pa0 + (size_t)64 * K, (bf16_t*)As + sOffA1);
    gld16(pb0, (bf16_t*)Bs + sOffA0);
    gld16(pb0 + (size_t)64 * K, (bf16_t*)Bs + sOffA1);
    __syncthreads();

    f32x4 acc[4][4] = {};
    int buf = 0;

    for (int k0 = 0; k0 < K; k0 += 32) {
        const int nb = buf ^ 1;
        if (k0 + 32 < K) {
            gld16(pa0 + k0 + 32, (bf16_t*)As + nb * 4096 + sOffA0);
            gld16(pa0 + (size_t)64 * K + k0 + 32, (bf16_t*)As + nb * 4096 + sOffA1);
            gld16(pb0 + k0 + 32, (bf16_t*)Bs + nb * 4096 + sOffA0);
            gld16(pb0 + (size_t)64 * K + k0 + 32, (bf16_t*)Bs + nb * 4096 + sOffA1);
        }
        const bf16_t* sA = (const bf16_t*)As + buf * 4096;
        const bf16_t* sB = (const bf16_t*)Bs + buf * 4096;
        bf16x8 af[4], bfr[4];
#pragma unroll
        for (int i = 0; i < 4; ++i)
            af[i] = *(const bf16x8*)(sA + (wm + i * 16 + m16) * 32 + quad * 8);
#pragma unroll
        for (int j = 0; j < 4; ++j)
            bfr[j] = *(const bf16x8*)(sB + (wn + j * 16 + m16) * 32 + quad * 8);
#pragma unroll
        for (int i = 0; i < 4; ++i)
#pragma unroll
            for (int j = 0; j < 4; ++j)
                acc[i][j] = __builtin_amdgcn_mfma_f32_16x16x32_bf16(af[i], bfr[j], acc[i][j], 0, 0, 0);
        __syncthreads();
        buf = nb;
    }

    const int b = m0 >> 11;
    if (n0 < 2 * DIM_) {
        // ---- q or k with fused RoPE ----
        const bool isq = (n0 < DIM_);
        const int  sg  = (m0 & (SEQ - 1)) + wm;  // + i*16 + quad*4 + r = seq pos
        const float osc = isq ? QK_SCALE : 1.0f;
        const bool even = ((m16 & 1) == 0);
#pragma unroll
        for (int j = 0; j < 4; ++j) {
            const int n = (n0 & (DIM_ - 1)) + wn + j * 16 + m16;
            const int h = n >> 6;
            const int t = (n & 63) >> 1;
            const int dout = even ? t : 32 + t;
            const float freq = exp2f(-ROPE_LF * (float)t);
            float stp_s, stp_c;
            sincosf(freq, &stp_s, &stp_c);       // rotation step (s -> s+1)
#pragma unroll
            for (int i = 0; i < 4; ++i) {
                float sa, ca;
                sincosf((float)(sg + i * 16 + quad * 4) * freq, &sa, &ca);
#pragma unroll
                for (int r = 0; r < 4; ++r) {
                    const float mine  = acc[i][j][r];
                    const float other = __shfl_xor(mine, 1);
                    const float outv  = (mine * ca + (even ? -other : other) * sa) * osc;
                    if (isq) {
                        qb[(size_t)(m0 + wm + i * 16 + quad * 4 + r) * DIM_ + h * 64 + dout] = (bf16_t)outv;
                    } else {
                        kt[((size_t)(b * 16 + h) * SEQ + (sg + i * 16 + quad * 4 + r)) * 64 + dout] = (bf16_t)outv;
                    }
                    // rotate (ca,sa) by step for next r
                    const float nc = ca * stp_c - sa * stp_s;
                    sa = sa * stp_c + ca * stp_s;
                    ca = nc;
                }
            }
        }
    } else {
        // ---- v: vt[((b*16+h)*128 + s/16)*64 + d][s%16] ----
#pragma unroll
        for (int j = 0; j < 4; ++j) {
            const int n = n0 - 2 * DIM_ + wn + j * 16 + m16;
            const int h = n >> 6;
            const int d = n & 63;
#pragma unroll
            for (int i = 0; i < 4; ++i) {
                const int s0 = (m0 & (SEQ - 1)) + wm + i * 16;
                const int kb = s0 >> 4;
                bf16x4 ov = { (bf16_t)acc[i][j][0], (bf16_t)acc[i][j][1],
                              (bf16_t)acc[i][j][2], (bf16_t)acc[i][j][3] };
                *(bf16x4*)(vt + ((size_t)((b * 16 + h) * 128 + kb) * 64 + d) * 16 + quad * 4) = ov;
            }
        }
    }
}

// ---------------------------------------------------------------------------
// Output GEMM, 128x64 tile, LDS double-buffer 2-phase (R8).
// ---------------------------------------------------------------------------
__global__ __launch_bounds__(256) void gemm_out64(const bf16_t* __restrict__ A,
                                                  const bf16_t* __restrict__ B,
                                                  const float* __restrict__ bias,
                                                  float* __restrict__ C,
                                                  int M, int N, int K) {
    __shared__ __align__(16) bf16_t As[2][128 * 32];
    __shared__ __align__(16) bf16_t Bs[2][64 * 32];
    const int tid  = threadIdx.x;
    const int m0   = blockIdx.y * 128;
    const int n0   = blockIdx.x * 64;
    const int w    = tid >> 6;
    const int lane = tid & 63;
    const int m16  = lane & 15;
    const int quad = lane >> 4;
    const int wm   = (w >> 1) * 64;
    const int wn   = (w & 1) * 32;
    const int lrow = lane >> 2;
    const int lcol = (lane & 3) * 8;

    const bf16_t* pa0 = A + (size_t)(m0 + w * 16 + lrow) * K + lcol;
    const bf16_t* pb0 = B + (size_t)(n0 + w * 16 + lrow) * K + lcol;
    const int sOff0 = (w * 16) * 32;
    const int sOff1 = (64 + w * 16) * 32;

    gld16(pa0, (bf16_t*)As + sOff0);
    gld16(pa0 + (size_t)64 * K, (bf16_t*)As + sOff1);
    gld16(pb0, (bf16_t*)Bs + sOff0);
    __syncthreads();

    f32x4 acc[4][2] = {};
    int buf = 0;

    for (int k0 = 0; k0 < K; k0 += 32) {
        const int nb = buf ^ 1;
        if (k0 + 32 < K) {
            gld16(pa0 + k0 + 32, (bf16_t*)As + nb * 4096 + sOff0);
            gld16(pa0 + (size_t)64 * K + k0 + 32, (bf16_t*)As + nb * 4096 + sOff1);
            gld16(pb0 + k0 + 32, (bf16_t*)Bs + nb * 2048 + sOff0);
        }
        const bf16_t* sA = (const bf16_t*)As + buf * 4096;
        const bf16_t* sB = (const bf16_t*)Bs + buf * 2048;
        bf16x8 af[4], bfr[2];
#pragma unroll
        for (int i = 0; i < 4; ++i)
            af[i] = *(const bf16x8*)(sA + (wm + i * 16 + m16) * 32 + quad * 8);
#pragma unroll
        for (int j = 0; j < 2; ++j)
            bfr[j] = *(const bf16x8*)(sB + (wn + j * 16 + m16) * 32 + quad * 8);
#pragma unroll
        for (int i = 0; i < 4; ++i)
#pragma unroll
            for (int j = 0; j < 2; ++j)
                acc[i][j] = __builtin_amdgcn_mfma_f32_16x16x32_bf16(af[i], bfr[j], acc[i][j], 0, 0, 0);
        __syncthreads();
        buf = nb;
    }

#pragma unroll
    for (int j = 0; j < 2; ++j) {
        const int col = n0 + wn + j * 16 + m16;
        const float bv = bias[col];
#pragma unroll
        for (int i = 0; i < 4; ++i)
#pragma unroll
            for (int r = 0; r < 4; ++r)
                C[(size_t)(m0 + wm + i * 16 + quad * 4 + r) * N + col] = acc[i][j][r] + bv;
    }
}

// ---------------------------------------------------------------------------
// Flash attention (R13). {depth-1 prefetch, XCD swizzle}: R12 showed the
// swizzle cuts FETCH 69.7->12.5 MB (K/V L2-resident per XCD) but depth-2's
// VGPR 136 dropped occupancy 4->3 waves/SIMD, cancelling the gain. This
// round: R11's 2-buffer ping-pong loop (VGPR ~120, 4 waves/SIMD) + the
// swizzled 1D grid. Barrier-free main loop, direct global fragment loads
// from compact layouts; LDS only for epilogue reductions.
// ---------------------------------------------------------------------------
__global__ __launch_bounds__(256) void attn_mfma(const bf16_t* __restrict__ qb,
                                                 const bf16_t* __restrict__ kt,
                                                 const bf16_t* __restrict__ vt,
                                                 bf16_t* __restrict__ out) {
    __shared__ __align__(16) char smem[17664];
    float* Ored = (float*)smem;               // 16640 B
    float* Lred = (float*)(smem + 16640);     // 1024 B

    const int tid  = threadIdx.x;
    const int w    = tid >> 6;
    const int lane = tid & 63;
    const int m16  = lane & 15;
    const int quad = lane >> 4;

    // XCD-bijective swizzle: 1024 blocks, XCD x owns swz [x*128, x*128+128)
    // = heads [x*4, x*4+4) (32 q-blocks per head) -> 2 MB K/V per XCD L2.
    const int bid = blockIdx.x;
    const int swz = (bid & 7) * 128 + (bid >> 3);
    const int bh  = swz >> 5;
    const int q0  = (swz & 31) * 64;
    const int b   = bh >> 4;
    const int hh  = bh & 15;

    // Q fragments from dense qb
    bf16x8 qf[4][2];
#pragma unroll
    for (int n = 0; n < 4; ++n)
#pragma unroll
        for (int c = 0; c < 2; ++c)
            qf[n][c] = *(const bf16x8*)(qb + (size_t)(b * SEQ + q0 + n * 16 + m16) * DIM_ +
                                        hh * HDIM + c * 32 + quad * 8);

    f32x4 o[4][4] = {};
    float lp[4] = {};

    // fragment pointers (tile 0); advance 4096 elements per tile
    const bf16_t* kp = kt + ((size_t)bh * SEQ + w * 16 + m16) * 64 + quad * 8;
    const bf16_t* vp = vt + (((size_t)bh * 128 + w) * 64 + m16) * 16 + quad * 4;

#define LOAD_TILE(AK0, AK1, VA)                                \
    do {                                                       \
        AK0 = *(const bf16x8*)(kp);                            \
        AK1 = *(const bf16x8*)(kp + 32);                       \
        VA[0] = *(const bf16x4*)(vp);                          \
        VA[1] = *(const bf16x4*)(vp + 256);                    \
        VA[2] = *(const bf16x4*)(vp + 512);                    \
        VA[3] = *(const bf16x4*)(vp + 768);                    \
        kp += 4096; vp += 4096;                                \
    } while (0)

#define COMPUTE_TILE(AK0, AK1, VA)                                                 \
    do {                                                                           \
        s16x4 pb[4];                                                               \
        _Pragma("unroll")                                                          \
        for (int n = 0; n < 4; ++n) {                                              \
            f32x4 c = {};                                                          \
            c = __builtin_amdgcn_mfma_f32_16x16x32_bf16(AK0, qf[n][0], c, 0, 0, 0); \
            c = __builtin_amdgcn_mfma_f32_16x16x32_bf16(AK1, qf[n][1], c, 0, 0, 0); \
            bf16x4 pv;                                                             \
            _Pragma("unroll")                                                      \
            for (int r = 0; r < 4; ++r) {                                          \
                const float pp = __builtin_amdgcn_exp2f(c[r]);                     \
                lp[n] += pp;                                                       \
                pv[r] = (bf16_t)pp;                                                \
            }                                                                      \
            pb[n] = as_s16x4(pv);                                                  \
        }                                                                          \
        __builtin_amdgcn_s_setprio(1);                                             \
        _Pragma("unroll")                                                          \
        for (int ds = 0; ds < 4; ++ds)                                             \
            _Pragma("unroll")                                                      \
            for (int n = 0; n < 4; ++n)                                            \
                o[ds][n] = __builtin_amdgcn_mfma_f32_16x16x16bf16_1k(               \
                    as_s16x4(VA[ds]), pb[n], o[ds][n], 0, 0, 0);                   \
        __builtin_amdgcn_s_setprio(0);                                             \
    } while (0)

    bf16x8 akA0, akA1, akB0, akB1;
    bf16x4 vaA[4], vaB[4];

    LOAD_TILE(akA0, akA1, vaA);          // tile 0
    for (int t = 0; t < 32; t += 2) {
        LOAD_TILE(akB0, akB1, vaB);      // tile t+1 (t<=30, always valid)
        COMPUTE_TILE(akA0, akA1, vaA);   // tile t
        if (t + 2 < 32)
            LOAD_TILE(akA0, akA1, vaA);  // tile t+2
        COMPUTE_TILE(akB0, akB1, vaB);   // tile t+1
    }
#undef LOAD_TILE
#undef COMPUTE_TILE

    // ---- l reduction: over quads (shfl), then over waves (LDS) ----
#pragma unroll
    for (int n = 0; n < 4; ++n) {
        lp[n] += __shfl_xor(lp[n], 16);
        lp[n] += __shfl_xor(lp[n], 32);
    }
    if (quad == 0) {
#pragma unroll
        for (int n = 0; n < 4; ++n) Lred[w * 64 + n * 16 + m16] = lp[n];
    }
    __syncthreads();
    const float linv = 1.0f / (Lred[lane] + Lred[64 + lane] + Lred[128 + lane] + Lred[192 + lane]);

    // ---- O reduction: 4 phases; all waves sum+store ----
    const size_t obase = (size_t)(b * SEQ + q0 + lane) * DIM_ + hh * HDIM;
#pragma unroll
    for (int p = 0; p < 4; ++p) {
        __syncthreads();
#pragma unroll
        for (int n = 0; n < 4; ++n)
#pragma unroll
            for (int r = 0; r < 4; ++r)
                Ored[w * 1040 + (quad * 4 + r) * 65 + n * 16 + m16] = o[p][n][r];
        __syncthreads();
        union { bf16_t e[4]; bf16x4 v; } ob;
#pragma unroll
        for (int d = 0; d < 4; ++d) {
            const int dd = w * 4 + d;
            const float v = Ored[dd * 65 + lane] + Ored[1040 + dd * 65 + lane] +
                            Ored[2080 + dd * 65 + lane] + Ored[3120 + dd * 65 + lane];
            ob.e[d] = (bf16_t)(v * linv);
        }
        *(bf16x4*)(out + obase + p * 16 + w * 4) = ob.v;
    }
}

// ---------------------------------------------------------------------------
extern "C" void kernel_launch(void* const* d_in, const int* in_sizes, int n_in,
                              void* d_out, int out_size, void* d_ws, size_t ws_size,
                              hipStream_t stream) {
    const float* x     = (const float*)d_in[0];
    const float* w_qkv = (const float*)d_in[1];
    const float* w_out = (const float*)d_in[2];
    const float* b_out = (const float*)d_in[3];
    float* out = (float*)d_out;

    const int M = BATCH * SEQ;  // 4096

    bf16_t* q_b    = (bf16_t*)d_ws;                         // 4096x1024
    bf16_t* attn_b = q_b + (size_t)M * DIM_;                // 4096x1024
    bf16_t* kt_b   = attn_b + (size_t)M * DIM_;             // 32 heads x 2048 x 64
    bf16_t* vt_b   = kt_b + (size_t)M * DIM_;               // 32 heads x 128 x 64 x 16
    bf16_t* xb     = vt_b + (size_t)M * DIM_;               // 4096x1024
    bf16_t* wqkvb  = xb + (size_t)M * DIM_;                 // 3072x1024
    bf16_t* woutb  = wqkvb + (size_t)3 * DIM_ * DIM_;       // 1024x1024

    // 0) cast x, w_qkv, w_out to bf16
    cast3<<<(XCNT + WQCNT + WOCNT) / (256 * 8), 256, 0, stream>>>(
        x, w_qkv, w_out, xb, wqkvb, woutb);

    // 1) qkv = x @ w_qkv^T with FUSED RoPE (q dense+scaled; k -> kt; v -> vt)
    gemm_qkv<<<dim3(3 * DIM_ / 128, M / 128), 256, 0, stream>>>(
        xb, wqkvb, q_b, kt_b, vt_b, M, 3 * DIM_, DIM_);

    // 2) flash attention -> attn_b (1D grid, XCD-swizzled)
    attn_mfma<<<SEQ / 64 * BATCH * NHEADS, 256, 0, stream>>>(q_b, kt_b, vt_b, attn_b);

    // 3) out = attn @ w_out^T + b_out (fp32), 128x64 tiles -> 512 blocks (2/CU)
    gemm_out64<<<dim3(DIM_ / 64, M / 128), 256, 0, stream>>>(
        attn_b, woutb, b_out, out, M, DIM_, DIM_);
}